// Round 19
// baseline (79.763 us; speedup 1.0000x reference)
//
#include <hip/hip_runtime.h>

#define NCODES 512
#define DIM 128
#define NROWS (64*2048)          // 131072
#define QN (NROWS*DIM)           // 16777216
#define ROWS_PER_WAVE 8
#define BLK_ROWS 32              // 4 waves x 8 rows
#define NBLOCKS (NROWS/BLK_ROWS) // 4096
#define NWAVES 4

__device__ __forceinline__ unsigned umin_(unsigned a, unsigned b) { return a < b ? a : b; }
__device__ __forceinline__ unsigned umax_(unsigned a, unsigned b) { return a > b ? a : b; }

// ---------------- prep: packed per-code table {w, beta, gamma, ss} ----------
// L_k(S,|x|) = w_k*S + beta_k - gamma_k*|x| <= d_k = w_k*(S+ss_k-2 x.e_k)
// (Cauchy-Schwarz; gamma inflated 1e-4 to dominate rounding).
__global__ void vq_prep(const float* __restrict__ emb, const float* __restrict__ scaling,
                        float4* __restrict__ tbl) {
  int k = blockIdx.x;
  int l = threadIdx.x; // 64 lanes
  float2 v = ((const float2*)(emb + k * DIM))[l];
  float ss = v.x * v.x + v.y * v.y;
#pragma unroll
  for (int m = 1; m < 64; m <<= 1) ss += __shfl_xor(ss, m);
  if (l == 0) {
    float hr = 40.0f + (float)k * (140.0f / 511.0f);
    float wt = 1.0f + scaling[k] * ((hr - 100.0f) * (1.0f / 70.0f));
    float4 t;
    t.x = wt;                                   // w
    t.y = wt * ss;                              // beta
    t.z = 2.0f * fabsf(wt) * sqrtf(ss) * (1.0f + 1e-4f);  // gamma
    t.w = ss;                                   // ||e||^2
    tbl[k] = t;
  }
}

// ---------------- main: 8-lanes/row bound scan, x in registers -------------
// 4096 blocks x 256 threads (4 waves x 8 rows; lane (q8,c8): row q8, dims
// c8*16..+15 in regs). Scan: codes strided k=j*8+c8 (64/lane, one float4
// table load each), packed-u32 min1/min2, 3-step merge across the row's 8
// lanes. Exact dot at kb from registers (NO x re-read). Verify: m2's bound
// > dW proves kb unique argmin; else cooperative brute force (exact,
// tie->smallest k; ~never fires: margin ~0.5 >> C-S slack ~0.15). Store via
// pos-layout: 512B-contiguous gathers, 1KB-contiguous stores (R12-proven).
__global__ __launch_bounds__(256, 6) void vq_main(
    const float* __restrict__ x,
    const float* __restrict__ emb32,
    const float4* __restrict__ tbl,
    float* __restrict__ out_q,
    float* __restrict__ out_idx,
    float* __restrict__ out_loss) {
  __shared__ float lossp[NWAVES];
  const int tid = threadIdx.x;
  const int wave = tid >> 6, lane = tid & 63;
  const int q8 = lane >> 3, c8 = lane & 7;
  const long rowW = (long)blockIdx.x * BLK_ROWS + wave * ROWS_PER_WAVE;

  // ---- Load x row-chunk into registers (64B/lane) + per-row S.
  float4 xr0, xr1, xr2, xr3;
  {
    const float4* xp = (const float4*)(x + (rowW + q8) * DIM + c8 * 16);
    xr0 = xp[0]; xr1 = xp[1]; xr2 = xp[2]; xr3 = xp[3];
  }
  float S;
  {
    float ssp = xr0.x*xr0.x + xr0.y*xr0.y + xr0.z*xr0.z + xr0.w*xr0.w
              + xr1.x*xr1.x + xr1.y*xr1.y + xr1.z*xr1.z + xr1.w*xr1.w
              + xr2.x*xr2.x + xr2.y*xr2.y + xr2.z*xr2.z + xr2.w*xr2.w
              + xr3.x*xr3.x + xr3.y*xr3.y + xr3.z*xr3.z + xr3.w*xr3.w;
    ssp += __shfl_xor(ssp, 1);
    ssp += __shfl_xor(ssp, 2);
    ssp += __shfl_xor(ssp, 4);
    S = ssp;                       // replicated across the row's 8 lanes
  }
  const float xn = sqrtf(S);

  // ---- Bound scan: 64 strided codes/lane, packed min1/min2.
  unsigned m1 = 0xFFFFFFFFu, m2 = 0xFFFFFFFFu;
#pragma unroll 8
  for (int j = 0; j < 64; ++j) {
    const int k = j * 8 + c8;
    float4 t = tbl[k];             // {w, beta, gamma, ss} — L1-hot 8KB
    float L = fmaf(-t.z, xn, fmaf(t.x, S, t.y));
    unsigned u = (__builtin_bit_cast(unsigned, L) & 0xFFFFFE00u) | (unsigned)k;
    unsigned mx = umax_(m1, u);
    m2 = umin_(m2, mx);
    m1 = umin_(m1, u);
  }
  // merge across the row's 8 lanes: (m1,m2) pair-combine.
#pragma unroll
  for (int m = 1; m <= 4; m <<= 1) {
    unsigned o1 = (unsigned)__shfl_xor((int)m1, m);
    unsigned o2 = (unsigned)__shfl_xor((int)m2, m);
    m2 = umin_(umin_(m2, o2), umax_(m1, o1));
    m1 = umin_(m1, o1);
  }
  const int kb = (int)(m1 & 511u);

  // ---- Exact f32 dot at kb (from registers; e chunk gathered, L1/L2-hot).
  float D, dW, wb;
  {
    const float4* ep = (const float4*)(emb32 + kb * DIM + c8 * 16);
    float4 e0 = ep[0], e1 = ep[1], e2 = ep[2], e3 = ep[3];
    float p = 0.f;
    p = fmaf(xr0.x, e0.x, p); p = fmaf(xr0.y, e0.y, p);
    p = fmaf(xr0.z, e0.z, p); p = fmaf(xr0.w, e0.w, p);
    p = fmaf(xr1.x, e1.x, p); p = fmaf(xr1.y, e1.y, p);
    p = fmaf(xr1.z, e1.z, p); p = fmaf(xr1.w, e1.w, p);
    p = fmaf(xr2.x, e2.x, p); p = fmaf(xr2.y, e2.y, p);
    p = fmaf(xr2.z, e2.z, p); p = fmaf(xr2.w, e2.w, p);
    p = fmaf(xr3.x, e3.x, p); p = fmaf(xr3.y, e3.y, p);
    p = fmaf(xr3.z, e3.z, p); p = fmaf(xr3.w, e3.w, p);
    p += __shfl_xor(p, 1);
    p += __shfl_xor(p, 2);
    p += __shfl_xor(p, 4);         // full dot, replicated
    float4 tb = tbl[kb];
    wb = tb.x;
    D = fmaf(-2.0f, p, S + tb.w);
    dW = wb * D;
  }

  // ---- Verify: second-smallest bound must exceed dW, else exact fallback.
  int win = kb;
  {
    const float m2L = __builtin_bit_cast(float, m2 & 0xFFFFFE00u);
    const float thr = fmaf(fabsf(dW), 1e-4f, dW + 1e-6f);
    const int cond = (m2L <= thr);
    if (__any(cond)) {
      // Cooperative exact brute force for all 8 rows (used only where cond).
      unsigned bmin = 0xFFFFFFFFu;
      float bD = 0.f;
      for (int k = 0; k < NCODES; ++k) {
        const float4* ep = (const float4*)(emb32 + k * DIM + c8 * 16);
        float4 e0 = ep[0], e1 = ep[1], e2 = ep[2], e3 = ep[3];
        float p = 0.f;
        p = fmaf(xr0.x, e0.x, p); p = fmaf(xr0.y, e0.y, p);
        p = fmaf(xr0.z, e0.z, p); p = fmaf(xr0.w, e0.w, p);
        p = fmaf(xr1.x, e1.x, p); p = fmaf(xr1.y, e1.y, p);
        p = fmaf(xr1.z, e1.z, p); p = fmaf(xr1.w, e1.w, p);
        p = fmaf(xr2.x, e2.x, p); p = fmaf(xr2.y, e2.y, p);
        p = fmaf(xr2.z, e2.z, p); p = fmaf(xr2.w, e2.w, p);
        p = fmaf(xr3.x, e3.x, p); p = fmaf(xr3.y, e3.y, p);
        p = fmaf(xr3.z, e3.z, p); p = fmaf(xr3.w, e3.w, p);
        p += __shfl_xor(p, 1);
        p += __shfl_xor(p, 2);
        p += __shfl_xor(p, 4);
        float4 t = tbl[k];
        float D2 = fmaf(-2.0f, p, S + t.w);
        float dw2 = t.x * D2;
        unsigned um = (__builtin_bit_cast(unsigned, dw2) & 0xFFFFFE00u) | (unsigned)k;
        if (um < bmin) { bmin = um; bD = D2; }   // row-uniform select
      }
      if (cond) { win = (int)(bmin & 511u); D = bD; }
    }
  }

  // ---- Indices + per-wave loss partial.
  if (c8 == 0) out_idx[rowW + q8] = (float)win;
  {
    float l0 = D;                  // replicated x8 per row
#pragma unroll
    for (int m = 1; m < 64; m <<= 1) l0 += __shfl_xor(l0, m);
    if (lane == 0) lossp[wave] = l0 * 0.125f;   // /8 replication
  }

  // ---- Store: pos-layout — gather 512B-contiguous, store 1KB-contiguous.
  {
    const float4* __restrict__ esrc = (const float4*)emb32;  // 32 f4/row
    float4* __restrict__ outu = (float4*)out_q + rowW * 32;
    const int hi = lane >> 5;
#pragma unroll
    for (int it = 0; it < 4; ++it) {
      const int pos = it * 64 + lane;
      const int row = it * 2 + hi;
      const int col = pos & 31;
      const int code = __shfl(win, row * 8);     // row's winner (c8=0 lane)
      outu[pos] = esrc[code * 32 + col];
    }
  }

  // ---- Block loss reduce + one atomic (4096 total).
  __syncthreads();
  if (wave == 0) {
    float s = (lane < NWAVES) ? lossp[lane] : 0.f;
    s += __shfl_xor(s, 1);
    s += __shfl_xor(s, 2);
    if (lane == 0) atomicAdd(out_loss, s * (1.6f / (float)QN));
  }
}

extern "C" void kernel_launch(void* const* d_in, const int* in_sizes, int n_in,
                              void* d_out, int out_size, void* d_ws, size_t ws_size,
                              hipStream_t stream) {
  const float* x = (const float*)d_in[0];
  const float* emb = (const float*)d_in[1];
  const float* scaling = (const float*)d_in[2];

  float* out_q = (float*)d_out;
  float* out_loss = out_q + QN;
  float* out_idx = out_q + QN + 1;

  float4* tbl = (float4*)d_ws;     // 8KB

  hipMemsetAsync(out_loss, 0, sizeof(float), stream);
  vq_prep<<<NCODES, 64, 0, stream>>>(emb, scaling, tbl);
  vq_main<<<NBLOCKS, 256, 0, stream>>>(x, emb, tbl, out_q, out_idx, out_loss);
}

// Round 21
// 43.406 us; speedup vs baseline: 1.8376x; 1.8376x over previous
//
#include <hip/hip_runtime.h>

#define NCODES 512
#define DIM 128
#define NROWS (64*2048)          // 131072
#define QN (NROWS*DIM)           // 16777216
#define BLK_ROWS 256
#define NBLOCKS (NROWS/BLK_ROWS) // 512
#define NWAVES 8                 // 512 threads, 32 rows/wave

typedef __attribute__((ext_vector_type(4))) float f32x4;

#define GLOAD_LDS16(gp, lp) __builtin_amdgcn_global_load_lds( \
    (__attribute__((address_space(1))) void*)(gp), \
    (__attribute__((address_space(3))) void*)(lp), 16, 0, 0)

// ---------------- prep: fp8 codebook (frag-ordered, x512) + weights --------
// Codebook ~U(+-1/512): scaled by 512 into e4m3 normal range (exact pow2,
// folded back via m2w = -2w/512). Layout is the MFMA B-fragment order:
// slice (t,c) = 512B; lane l's 8B at slice+l*8 holds code t*16+(l&15), dims
// c*32+(l>>4)*8..+7. vq_main stages LINEARLY. (Validated R13/R14/R16.)
__global__ void vq_prep(const float* __restrict__ emb, const float* __restrict__ scaling,
                        unsigned char* __restrict__ e8frag,
                        float* __restrict__ wv, float* __restrict__ wse,
                        float* __restrict__ wrcp) {
  int k = blockIdx.x;
  int l = threadIdx.x; // 64 lanes; dims d=2l, 2l+1
  float2 v = ((const float2*)(emb + k * DIM))[l];
  float ss = v.x * v.x + v.y * v.y;
#pragma unroll
  for (int m = 1; m < 64; m <<= 1) ss += __shfl_xor(ss, m);
  int p = __builtin_amdgcn_cvt_pk_fp8_f32(v.x * 512.0f, v.y * 512.0f, 0, false);
  int t = k >> 4, col = k & 15;
  int c = l >> 4, g = (l >> 2) & 3, jp = l & 3;
  *(unsigned short*)(e8frag + (((t * 4 + c) * 64 + g * 16 + col) << 3) + 2 * jp) =
      (unsigned short)(p & 0xFFFF);
  if (l == 0) {
    float hr = 40.0f + (float)k * (140.0f / 511.0f);
    float wt = 1.0f + scaling[k] * ((hr - 100.0f) * (1.0f / 70.0f));
    wv[k] = wt;
    wse[k] = wt * ss;        // w_k * ||e_k||^2 (exact f32)
    wrcp[k] = 1.0f / wt;
  }
}

// ---------------- main ----------------
// Best measured structure (R13, 41.5us steady): 512 blocks x 512 threads
// (8 waves x 32 rows, B-reuse 2), full fp8 codebook 64KB -> 72KB LDS,
// 2 blocks/CU, ONE barrier, packed-u32 argmin (dist>=0 -> u32 order ==
// (dist,code) -> min = argmin, tie->smaller code), T14 store, atomic loss.
// R20/21 delta: T5 s_setprio(1) around the MFMA cluster — waves drift
// through different phases after the single barrier (attn-like regime where
// T5 measured +4-7%), so prioritizing MFMA-issuing waves can help.
struct SmemT {
  unsigned char frag[NCODES * DIM]; // 65536 B fp8, fragment-ordered
  float w[NCODES];
  float wse[NCODES];
  float wrcp[NCODES];
  float lossp[NWAVES];
};

__global__ __launch_bounds__(512, 4) void vq_main(
    const float* __restrict__ x,
    const float* __restrict__ emb32,
    const unsigned char* __restrict__ e8frag,
    const float* __restrict__ wv,
    const float* __restrict__ wse,
    const float* __restrict__ wrcp,
    float* __restrict__ out_q,
    float* __restrict__ out_idx,
    float* __restrict__ out_loss) {
  __shared__ SmemT sm;
  const int tid = threadIdx.x;
  const int wave = tid >> 6, lane = tid & 63;
  const int g = lane >> 4, lr = lane & 15;
  const long rowbase = (long)blockIdx.x * BLK_ROWS + wave * 32;

  // --- Issue x loads (f32, registers) ---
  float4 xv[2][4][2];
#pragma unroll
  for (int rg = 0; rg < 2; rg++) {
    const float* xr = x + (rowbase + rg * 16 + lr) * DIM + g * 8;
#pragma unroll
    for (int c = 0; c < 4; c++) {
      xv[rg][c][0] = *(const float4*)(xr + c * 32);
      xv[rg][c][1] = *(const float4*)(xr + c * 32 + 4);
    }
  }

  // --- Stage fp8 codebook: LINEAR global_load_lds (prep pre-ordered).
  {
#pragma unroll
    for (int i = 0; i < 8; i++) {
      int slot = i * 512 + tid;            // 16B slot 0..4095
      GLOAD_LDS16(e8frag + slot * 16, sm.frag + slot * 16);
    }
    sm.w[tid] = wv[tid]; sm.wse[tid] = wse[tid]; sm.wrcp[tid] = wrcp[tid];
  }

  // --- Convert x to fp8 A fragments + row sumsq (f32-exact S).
  long a[2][4];
  float sr[2][4];
  {
    float srow[2];
#pragma unroll
    for (int rg = 0; rg < 2; rg++) {
      float ss = 0.f;
#pragma unroll
      for (int c = 0; c < 4; c++) {
        float4 v0 = xv[rg][c][0];
        float4 v1 = xv[rg][c][1];
        ss += v0.x * v0.x + v0.y * v0.y + v0.z * v0.z + v0.w * v0.w;
        ss += v1.x * v1.x + v1.y * v1.y + v1.z * v1.z + v1.w * v1.w;
        int lo = __builtin_amdgcn_cvt_pk_fp8_f32(v0.x, v0.y, 0, false);
        lo = __builtin_amdgcn_cvt_pk_fp8_f32(v0.z, v0.w, lo, true);
        int hi = __builtin_amdgcn_cvt_pk_fp8_f32(v1.x, v1.y, 0, false);
        hi = __builtin_amdgcn_cvt_pk_fp8_f32(v1.z, v1.w, hi, true);
        a[rg][c] = (long)(((unsigned long long)(unsigned)hi << 32) |
                          (unsigned long long)(unsigned)lo);
      }
      ss += __shfl_xor(ss, 16);
      ss += __shfl_xor(ss, 32);
      srow[rg] = ss;
    }
#pragma unroll
    for (int rg = 0; rg < 2; rg++)
#pragma unroll
      for (int r = 0; r < 4; r++)
        sr[rg][r] = __shfl(srow[rg], g * 4 + r);  // ||x||^2 of C-row 4g+r
  }
  __syncthreads();  // codebook staged; LDS read-only until loss phase

  // --- Sweep 32 column tiles of 16 codes; packed-u32 running argmin.
  unsigned pmin[2][4];
#pragma unroll
  for (int rg = 0; rg < 2; rg++)
#pragma unroll
    for (int r = 0; r < 4; r++) pmin[rg][r] = 0xFFFFFFFFu;

  const long* __restrict__ bbase = (const long*)sm.frag + lane;
#pragma unroll 2
  for (int t = 0; t < 32; t++) {
    const unsigned code = t * 16 + lr;    // B col = lane&15
    const float wt = sm.w[code];
    const float bb = sm.wse[code];
    const float m2w = -2.0f * wt * (1.0f / 512.0f);  // undo codebook x512
    f32x4 acc0 = {0.f, 0.f, 0.f, 0.f};
    f32x4 acc1 = {0.f, 0.f, 0.f, 0.f};
    __builtin_amdgcn_s_setprio(1);        // T5: favor MFMA-issuing wave
#pragma unroll
    for (int c = 0; c < 4; c++) {
      long bf = bbase[(t * 4 + c) * 64];
      acc0 = __builtin_amdgcn_mfma_f32_16x16x32_fp8_fp8(a[0][c], bf, acc0, 0, 0, 0);
      acc1 = __builtin_amdgcn_mfma_f32_16x16x32_fp8_fp8(a[1][c], bf, acc1, 0, 0, 0);
    }
    __builtin_amdgcn_s_setprio(0);
#pragma unroll
    for (int r = 0; r < 4; r++) {
      float v0 = fmaf(m2w, acc0[r], fmaf(wt, sr[0][r], bb));
      float v1 = fmaf(m2w, acc1[r], fmaf(wt, sr[1][r], bb));
      unsigned u0 = (__builtin_bit_cast(unsigned, v0) & 0xFFFFFE00u) | code;
      unsigned u1 = (__builtin_bit_cast(unsigned, v1) & 0xFFFFFE00u) | code;
      pmin[0][r] = min(pmin[0][r], u0);
      pmin[1][r] = min(pmin[1][r], u1);
    }
  }

  // --- Butterfly min across the 16 lanes of each group.
#pragma unroll
  for (int m = 1; m <= 8; m <<= 1) {
#pragma unroll
    for (int rg = 0; rg < 2; rg++)
#pragma unroll
      for (int r = 0; r < 4; r++) {
        unsigned o = (unsigned)__shfl_xor((int)pmin[rg][r], m);
        pmin[rg][r] = min(pmin[rg][r], o);
      }
  }

  // --- T14 store: issue 8 gathers, bookkeeping under latency, write; repeat.
  const uint4* __restrict__ esrc = (const uint4*)emb32;   // 32 uint4/row
  uint4* __restrict__ outu = (uint4*)out_q + rowbase * 32;
  const int col = lane & 31;
  const int hi2 = lane >> 5;                // 0: row 2it, 1: row 2it+1
  int scode[16];
#pragma unroll
  for (int it = 0; it < 16; it++) {
    const int row0 = 2 * it;                // compile-time
    const int rg = row0 >> 4;
    const int gn = (row0 >> 2) & 3;
    const int r0 = row0 & 3;                // even
    int c0 = __shfl((int)pmin[rg][r0], gn * 16);
    int c1 = __shfl((int)pmin[rg][r0 + 1], gn * 16);
    scode[it] = (hi2 ? c1 : c0) & 511;
  }

  uint4 vbuf[8];
#pragma unroll
  for (int j = 0; j < 8; j++)
    vbuf[j] = esrc[scode[j] * 32 + col];    // in flight...

  // ...bookkeeping under gather latency: indices + per-wave loss partial.
  {
    float l0 = 0.f;
#pragma unroll
    for (int rg = 0; rg < 2; rg++)
#pragma unroll
      for (int r = 0; r < 4; r++) {
        unsigned wn = pmin[rg][r];
        int ci = (int)(wn & 511u);
        float dist = __builtin_bit_cast(float, wn & 0xFFFFFE00u);
        l0 = fmaf(dist, sm.wrcp[ci], l0);
        if (lr == 0) out_idx[rowbase + rg * 16 + g * 4 + r] = (float)ci;
      }
    l0 += __shfl_xor(l0, 16);
    l0 += __shfl_xor(l0, 32);
    if (lane == 0) sm.lossp[wave] = l0;
  }

#pragma unroll
  for (int j = 0; j < 8; j++)
    outu[j * 64 + lane] = vbuf[j];
#pragma unroll
  for (int j = 0; j < 8; j++)
    vbuf[j] = esrc[scode[8 + j] * 32 + col];
#pragma unroll
  for (int j = 0; j < 8; j++)
    outu[(8 + j) * 64 + lane] = vbuf[j];

  // --- Per-block loss reduce + one atomic (512 atomics total).
  __syncthreads();
  if (wave == 0 && lane < NWAVES) {
    float s = sm.lossp[lane];
#pragma unroll
    for (int m = 1; m < NWAVES; m <<= 1) s += __shfl_xor(s, m);
    if (lane == 0) atomicAdd(out_loss, s * (1.6f / (float)QN));
  }
}

extern "C" void kernel_launch(void* const* d_in, const int* in_sizes, int n_in,
                              void* d_out, int out_size, void* d_ws, size_t ws_size,
                              hipStream_t stream) {
  const float* x = (const float*)d_in[0];
  const float* emb = (const float*)d_in[1];
  const float* scaling = (const float*)d_in[2];

  float* out_q = (float*)d_out;
  float* out_loss = out_q + QN;
  float* out_idx = out_q + QN + 1;

  unsigned char* e8frag = (unsigned char*)d_ws;                   // 64KB
  float* wv = (float*)((char*)d_ws + NCODES * DIM);               // 2KB
  float* wse = wv + NCODES;                                       // 2KB
  float* wrcp = wse + NCODES;                                     // 2KB

  hipMemsetAsync(out_loss, 0, sizeof(float), stream);
  vq_prep<<<NCODES, 64, 0, stream>>>(emb, scaling, e8frag, wv, wse, wrcp);
  vq_main<<<NBLOCKS, 512, 0, stream>>>(x, emb, e8frag, wv, wse, wrcp,
                                       out_q, out_idx, out_loss);
}